// Round 10
// baseline (91.291 us; speedup 1.0000x reference)
//
#include <hip/hip_runtime.h>
#include <hip/hip_bf16.h>

#define BATCHN 16
#define SEQ 4096
#define HIDDEN 128
#define STATE 256
#define MTOT (BATCHN*SEQ)    // 65536
#define LCHUNK 32            // timesteps per tile (halved: shorter serial phases)
#define NCHUNK 128           // SEQ / LCHUNK
#define NTILE (MTOT/LCHUNK)  // 2048 tiles -> ~1.6 generations at 5 blocks/CU

typedef __bf16 bf16;
typedef __bf16 bf16x4 __attribute__((ext_vector_type(4)));
typedef __bf16 bf16x8 __attribute__((ext_vector_type(8)));
typedef float f32x4 __attribute__((ext_vector_type(4)));

__device__ __forceinline__ void scan_params(const float* __restrict__ A_diag,
        const float* __restrict__ steps, int n,
        float& m11, float& m12, float& m21, float& m22, float& c1, float& c2) {
    float st = 1.0f / (1.0f + expf(-steps[n]));
    float A  = fmaxf(A_diag[n], 0.0f);
    float s2A = st * st * A;
    float schur = 1.0f / (1.0f + s2A);
    m11 = 1.0f - s2A * schur;
    m12 = -st * A * schur;
    m21 = st * schur;
    m22 = schur;
    c1 = m11 * st;
    c2 = m21 * st;
}

// ---------------- setup: bf16 copies of B, C ----------------
__global__ __launch_bounds__(256) void setup_k(const float* __restrict__ Bm,
        const float* __restrict__ Cm, bf16* __restrict__ Bbf, bf16* __restrict__ Cbf) {
    int idx = blockIdx.x * 256 + threadIdx.x;   // grid 128 -> 32768 = STATE*HIDDEN
    Bbf[idx] = (bf16)Bm[idx];
    Cbf[idx] = (bf16)Cm[idx];
}

// Shared tile prologue: stage x into bu cols [0,128), GEMM1 into bu cols [0,256).
// bu is 17 KB -> 5 blocks/CU at launch_bounds(256,5).
__device__ __forceinline__ void tile_gemm1(const float* __restrict__ x,
        const bf16* __restrict__ Bbf, int m0, int tid, bf16 (*bu)[264]) {
    const int lane = tid & 63;
    const int lr = lane & 15, lk = (lane >> 4) * 8;
    const int n0 = (tid >> 6) * 64;
    const int mrow = (lane >> 4) * 4;
    // stage x (fp32 -> bf16) into bu cols [0,128)
    #pragma unroll
    for (int p = 0; p < 4; ++p) {
        int flat = p * 256 + tid;                // 32 rows x 32 float4
        int row = flat >> 5, c4 = flat & 31;
        float4 v = *reinterpret_cast<const float4*>(&x[(size_t)(m0 + row) * HIDDEN + c4 * 4]);
        bf16x4 w = { (bf16)v.x, (bf16)v.y, (bf16)v.z, (bf16)v.w };
        *reinterpret_cast<bf16x4*>(&bu[row][c4 * 4]) = w;
    }
    __syncthreads();
    // GEMM1: Bu = x @ B^T (A from aliased bu cols, B inline bf16 16B loads, L2-hot)
    f32x4 acc[2][4];
    #pragma unroll
    for (int i = 0; i < 2; ++i)
        #pragma unroll
        for (int j = 0; j < 4; ++j) acc[i][j] = f32x4{0.f, 0.f, 0.f, 0.f};
    #pragma unroll
    for (int ks = 0; ks < 4; ++ks) {
        int k = ks * 32 + lk;
        bf16x8 a[2], bfr[4];
        #pragma unroll
        for (int mf = 0; mf < 2; ++mf)
            a[mf] = *reinterpret_cast<const bf16x8*>(&bu[mf * 16 + lr][k]);
        #pragma unroll
        for (int nf = 0; nf < 4; ++nf)
            bfr[nf] = *reinterpret_cast<const bf16x8*>(
                &Bbf[(size_t)(n0 + nf * 16 + lr) * HIDDEN + k]);
        #pragma unroll
        for (int mf = 0; mf < 2; ++mf)
            #pragma unroll
            for (int nf = 0; nf < 4; ++nf)
                acc[mf][nf] = __builtin_amdgcn_mfma_f32_16x16x32_bf16(a[mf], bfr[nf], acc[mf][nf], 0, 0, 0);
    }
    __syncthreads();                              // all A reads done before overwrite
    #pragma unroll
    for (int mf = 0; mf < 2; ++mf)
        #pragma unroll
        for (int nf = 0; nf < 4; ++nf)
            #pragma unroll
            for (int r = 0; r < 4; ++r)
                bu[mf * 16 + mrow + r][n0 + nf * 16 + lr] = (bf16)acc[mf][nf][r];
}

// ---------------- K1s: GEMM1 -> local scanA (32 steps) -> cs ----------------
__global__ __launch_bounds__(256, 5) void k1s(const float* __restrict__ x,
        const bf16* __restrict__ Bbf, const float* __restrict__ A_diag,
        const float* __restrict__ steps, float* __restrict__ cs) {
    __shared__ bf16 bu[32][264];                  // 16.9 KB
    const int tid = threadIdx.x;
    const int bid = blockIdx.x;                   // = batch*NCHUNK + chunk
    const int m0 = bid * LCHUNK;
    tile_gemm1(x, Bbf, m0, tid, bu);
    const int n = tid;
    float m11, m12, m21, m22, c1, c2;
    scan_params(A_diag, steps, n, m11, m12, m21, m22, c1, c2);
    __syncthreads();
    float s1 = 0.f, s2 = 0.f;
    #pragma unroll 8
    for (int t = 0; t < LCHUNK; ++t) {
        float v = (float)bu[t][n];
        float ns1 = fmaf(m11, s1, fmaf(m12, s2, c1 * v));
        float ns2 = fmaf(m21, s1, fmaf(m22, s2, c2 * v));
        s1 = ns1; s2 = ns2;
    }
    size_t base = ((size_t)bid * 2) * STATE + n;
    cs[base] = s1;                                // inclusive local chunk summary
    cs[base + STATE] = s2;
}

// ---------------- comb2: pair-fold + Kogge-Stone over 64 lane-pairs ----------------
// lane l owns chunks (2l, 2l+1). Pair summary w = M32*v(2l) + v(2l+1), pair
// propagator M64. KS over lanes; redistribute exclusive to both chunks.
__global__ __launch_bounds__(256) void comb2(float* __restrict__ cs,
        const float* __restrict__ A_diag, const float* __restrict__ steps) {
    const int l    = threadIdx.x & 63;
    const int nsub = threadIdx.x >> 6;            // 0..3
    const int b    = blockIdx.x >> 2;
    const int nb   = blockIdx.x & 3;
    #pragma unroll 2
    for (int i = 0; i < 16; ++i) {
        const int n = nb * 64 + i * 4 + nsub;
        float m11, m12, m21, m22, cu1, cu2;
        scan_params(A_diag, steps, n, m11, m12, m21, m22, cu1, cu2);
        // M32 = M^32 (5 squarings)
        float a11 = m11, a12 = m12, a21 = m21, a22 = m22;
        #pragma unroll
        for (int r = 0; r < 5; ++r) {
            float q11 = a11 * a11 + a12 * a21;
            float q12 = a11 * a12 + a12 * a22;
            float q21 = a21 * a11 + a22 * a21;
            float q22 = a21 * a12 + a22 * a22;
            a11 = q11; a12 = q12; a21 = q21; a22 = q22;
        }
        // M64 = M32^2
        float p11 = a11 * a11 + a12 * a21;
        float p12 = a11 * a12 + a12 * a22;
        float p21 = a21 * a11 + a22 * a21;
        float p22 = a21 * a12 + a22 * a22;
        size_t base0 = ((size_t)(b * NCHUNK + 2 * l) * 2) * STATE + n;
        size_t base1 = ((size_t)(b * NCHUNK + 2 * l + 1) * 2) * STATE + n;
        float v01 = cs[base0], v02 = cs[base0 + STATE];
        float v11 = cs[base1], v12 = cs[base1 + STATE];
        // pair summary
        float W1 = fmaf(a11, v01, fmaf(a12, v02, v11));
        float W2 = fmaf(a21, v01, fmaf(a22, v02, v12));
        // KS inclusive over 64 lanes, propagator P starts at M64, squares each round
        float q11 = p11, q12 = p12, q21 = p21, q22 = p22;
        #pragma unroll
        for (int r = 0; r < 6; ++r) {
            int d = 1 << r;
            float U1 = __shfl_up(W1, d, 64);
            float U2 = __shfl_up(W2, d, 64);
            if (l >= d) {
                W1 = fmaf(q11, U1, fmaf(q12, U2, W1));
                W2 = fmaf(q21, U1, fmaf(q22, U2, W2));
            }
            float t11 = q11 * q11 + q12 * q21;
            float t12 = q11 * q12 + q12 * q22;
            float t21 = q21 * q11 + q22 * q21;
            float t22 = q21 * q12 + q22 * q22;
            q11 = t11; q12 = t12; q21 = t21; q22 = t22;
        }
        // exclusive pair prefix
        float E1 = __shfl_up(W1, 1, 64);
        float E2 = __shfl_up(W2, 1, 64);
        if (l == 0) { E1 = 0.f; E2 = 0.f; }
        // chunk 2l init = E; chunk 2l+1 init = M32*E + v(2l)
        cs[base0] = E1;
        cs[base0 + STATE] = E2;
        float F1 = fmaf(a11, E1, fmaf(a12, E2, v01));
        float F2 = fmaf(a21, E1, fmaf(a22, E2, v02));
        cs[base1] = F1;
        cs[base1 + STATE] = F2;
    }
}

// ---------------- K2s: GEMM1 (recompute) -> scanC -> GEMM2 -> D*x ----------------
__global__ __launch_bounds__(256, 5) void k2s(const float* __restrict__ x,
        const bf16* __restrict__ Bbf, const bf16* __restrict__ Cbf,
        const float* __restrict__ A_diag, const float* __restrict__ steps,
        const float* __restrict__ cs, const float* __restrict__ Dv,
        float* __restrict__ out) {
    __shared__ bf16 bu[32][264];
    float (*ldsF)[132] = reinterpret_cast<float(*)[132]>(&bu[0][0]);
    const int tid = threadIdx.x;
    const int bid = blockIdx.x;
    const int m0 = bid * LCHUNK;
    const int lane = tid & 63;
    const int lr = lane & 15, lk = (lane >> 4) * 8;
    const int h0 = (tid >> 6) * 32;
    const int mrow = (lane >> 4) * 4;

    tile_gemm1(x, Bbf, m0, tid, bu);              // bit-identical Bu tile in LDS

    const int n = tid;
    float m11, m12, m21, m22, c1, c2;
    scan_params(A_diag, steps, n, m11, m12, m21, m22, c1, c2);
    size_t cbase = ((size_t)bid * 2) * STATE + n;
    float s1 = cs[cbase], s2 = cs[cbase + STATE]; // exclusive init state
    __syncthreads();

    // scanC: overwrite bu with y (bf16)
    #pragma unroll 8
    for (int t = 0; t < LCHUNK; ++t) {
        float v = (float)bu[t][n];
        float ns1 = fmaf(m11, s1, fmaf(m12, s2, c1 * v));
        float ns2 = fmaf(m21, s1, fmaf(m22, s2, c2 * v));
        s1 = ns1; s2 = ns2;
        bu[t][n] = (bf16)s2;
    }
    __syncthreads();

    // GEMM2: y @ C^T (inline bf16 C frags, L2-hot)
    f32x4 acc2[2][2];
    #pragma unroll
    for (int i = 0; i < 2; ++i) {
        acc2[i][0] = f32x4{0.f, 0.f, 0.f, 0.f};
        acc2[i][1] = f32x4{0.f, 0.f, 0.f, 0.f};
    }
    #pragma unroll
    for (int ks = 0; ks < 8; ++ks) {
        int k = ks * 32 + lk;
        bf16x8 a[2], cfr[2];
        #pragma unroll
        for (int mf = 0; mf < 2; ++mf)
            a[mf] = *reinterpret_cast<const bf16x8*>(&bu[mf * 16 + lr][k]);
        #pragma unroll
        for (int hf = 0; hf < 2; ++hf)
            cfr[hf] = *reinterpret_cast<const bf16x8*>(
                &Cbf[(size_t)(h0 + hf * 16 + lr) * STATE + k]);
        #pragma unroll
        for (int mf = 0; mf < 2; ++mf)
            #pragma unroll
            for (int hf = 0; hf < 2; ++hf)
                acc2[mf][hf] = __builtin_amdgcn_mfma_f32_16x16x32_bf16(a[mf], cfr[hf], acc2[mf][hf], 0, 0, 0);
    }
    __syncthreads();                              // all bu reads done before fp32 reuse
    #pragma unroll
    for (int mf = 0; mf < 2; ++mf)
        #pragma unroll
        for (int hf = 0; hf < 2; ++hf)
            #pragma unroll
            for (int r = 0; r < 4; ++r)
                ldsF[mf * 16 + mrow + r][h0 + hf * 16 + lr] = acc2[mf][hf][r];
    __syncthreads();

    // coalesced epilogue: out = ldsF + D*x (x fp32, L3-hot re-read)
    #pragma unroll
    for (int p = 0; p < 4; ++p) {
        int flat = p * 256 + tid;
        int row = flat >> 5, c4 = flat & 31;
        float4 xv = *reinterpret_cast<const float4*>(&x[(size_t)(m0 + row) * HIDDEN + c4 * 4]);
        float4 f = *reinterpret_cast<const float4*>(&ldsF[row][c4 * 4]);
        float4 d = *reinterpret_cast<const float4*>(&Dv[c4 * 4]);
        float4 o;
        o.x = f.x + d.x * xv.x;
        o.y = f.y + d.y * xv.y;
        o.z = f.z + d.z * xv.z;
        o.w = f.w + d.w * xv.w;
        *reinterpret_cast<float4*>(&out[(size_t)(m0 + row) * HIDDEN + c4 * 4]) = o;
    }
}

extern "C" void kernel_launch(void* const* d_in, const int* in_sizes, int n_in,
                              void* d_out, int out_size, void* d_ws, size_t ws_size,
                              hipStream_t stream) {
    const float* x      = (const float*)d_in[0];
    const float* A_diag = (const float*)d_in[1];
    const float* steps  = (const float*)d_in[2];
    const float* Bm     = (const float*)d_in[3];
    const float* Cm     = (const float*)d_in[4];
    const float* Dv     = (const float*)d_in[5];
    float* out = (float*)d_out;

    char* ws = (char*)d_ws;
    const size_t CS_BYTES = (size_t)NTILE * 2 * STATE * 4;   // 4 MB
    float* cs  = (float*)ws;
    bf16*  Bbf = (bf16*)(ws + CS_BYTES);
    bf16*  Cbf = (bf16*)(ws + CS_BYTES + (size_t)STATE * HIDDEN * 2);

    hipLaunchKernelGGL(setup_k, dim3(128), dim3(256), 0, stream, Bm, Cm, Bbf, Cbf);
    hipLaunchKernelGGL(k1s, dim3(NTILE), dim3(256), 0, stream, x, Bbf, A_diag, steps, cs);
    hipLaunchKernelGGL(comb2, dim3(BATCHN * 4), dim3(256), 0, stream, cs, A_diag, steps);
    hipLaunchKernelGGL(k2s, dim3(NTILE), dim3(256), 0, stream,
                       x, Bbf, Cbf, A_diag, steps, cs, Dv, out);
}